// Round 1
// baseline (2622.445 us; speedup 1.0000x reference)
//
#include <hip/hip_runtime.h>

typedef unsigned short u16;
typedef unsigned int   u32;
typedef __bf16 bf16x8 __attribute__((ext_vector_type(8)));
typedef float  f32x4  __attribute__((ext_vector_type(4)));

#define B_  8
#define T_  2048
#define D_  1024
#define H_  8
#define C_  64
#define DV_ 128
#define M_  (B_*T_)   // 16384

__device__ __forceinline__ u16 f2bf(float f){
  u32 u = __float_as_uint(f);
  u32 r = (u + 0x7fffu + ((u >> 16) & 1u)) >> 16;   // RNE
  return (u16)r;
}

// ---------------- LayerNorm: x (M,1024) f32 -> xn bf16 ----------------
__global__ __launch_bounds__(256) void ln_kernel(
    const float* __restrict__ x, const float* __restrict__ gamma,
    const float* __restrict__ beta, u16* __restrict__ xnb){
  const int m = blockIdx.x;
  const int tid = threadIdx.x;
  const int wave = tid >> 6, lane = tid & 63;
  const float* xr = x + (size_t)m * D_;
  float4 xv = *(const float4*)&xr[tid*4];
  float s = xv.x + xv.y + xv.z + xv.w;
  #pragma unroll
  for (int off = 32; off > 0; off >>= 1) s += __shfl_xor(s, off, 64);
  __shared__ float red[8];
  if (lane == 0) red[wave] = s;
  __syncthreads();
  float mu = (red[0]+red[1]+red[2]+red[3]) * (1.f/1024.f);
  float dx = xv.x-mu, dy = xv.y-mu, dz = xv.z-mu, dw = xv.w-mu;
  float ss = dx*dx + dy*dy + dz*dz + dw*dw;
  #pragma unroll
  for (int off = 32; off > 0; off >>= 1) ss += __shfl_xor(ss, off, 64);
  if (lane == 0) red[4+wave] = ss;
  __syncthreads();
  float var = (red[4]+red[5]+red[6]+red[7]) * (1.f/1024.f);
  float rs = rsqrtf(var + 1e-5f);
  float4 g  = *(const float4*)&gamma[tid*4];
  float4 bb = *(const float4*)&beta[tid*4];
  ushort4 o4;
  o4.x = f2bf(dx*rs*g.x + bb.x);
  o4.y = f2bf(dy*rs*g.y + bb.y);
  o4.z = f2bf(dz*rs*g.z + bb.z);
  o4.w = f2bf(dw*rs*g.w + bb.w);
  *(ushort4*)&xnb[(size_t)m*D_ + tid*4] = o4;
}

// ------------- weight prep: convert/concat/transpose to bf16 -------------
// Wcatb rows: [0,64)=Wq, [64,128)=Wk, [128,192)=Wv, [192,704)=Wa_w  (704x1024)
// QcTb[n=h*64+e][c] = Qc[h][c][e]   (512x64)
// VcTb[n=h*128+d][c] = Vc[h][c][d]  (1024x64)
// Wob = Wo bf16                      (1024x1024)
__global__ __launch_bounds__(256) void prep_weights(
    const float* __restrict__ Wq, const float* __restrict__ Wk,
    const float* __restrict__ Wv, const float* __restrict__ Wa,
    const float* __restrict__ Qc, const float* __restrict__ Vc,
    const float* __restrict__ Wo,
    u16* __restrict__ Wcatb, u16* __restrict__ QcTb,
    u16* __restrict__ VcTb,  u16* __restrict__ Wob){
  int idx = blockIdx.x * 256 + threadIdx.x;
  if (idx < 720896){                       // 704*1024
    int r = idx >> 10, col = idx & 1023;
    float v;
    if (r < 64)       v = Wq[(size_t)r*1024 + col];
    else if (r < 128) v = Wk[(size_t)(r-64)*1024 + col];
    else if (r < 192) v = Wv[(size_t)(r-128)*1024 + col];
    else              v = Wa[(size_t)(r-192)*1024 + col];
    Wcatb[idx] = f2bf(v);
  } else if (idx < 753664){                // +512*64
    int i = idx - 720896;
    int n = i >> 6, c = i & 63; int h = n >> 6, e = n & 63;
    QcTb[i] = f2bf(Qc[((size_t)h*64 + c)*64 + e]);
  } else if (idx < 819200){                // +1024*64
    int i = idx - 753664;
    int n = i >> 6, c = i & 63; int h = n >> 7, d = n & 127;
    VcTb[i] = f2bf(Vc[((size_t)h*64 + c)*128 + d]);
  } else if (idx < 1867776){               // +1024*1024
    int i = idx - 819200;
    Wob[i] = f2bf(Wo[i]);
  }
}

// ------------- generic bf16 MFMA GEMM: C[M,N] = A[M,K] @ Bw[N,K]^T (+res) ---
// BM=128, BN=64, BK=32; 256 threads = 4 waves; wave w: rows [w*32,w*32+32)
// mfma_f32_16x16x32_bf16: A frag A[m=lane&15][k=(lane>>4)*8+j];
// B frag Bw[n=lane&15][k=(lane>>4)*8+j]; D: col=lane&15, row=(lane>>4)*4+reg.
__global__ __launch_bounds__(256) void gemm_bf16(
    const u16* __restrict__ A, const u16* __restrict__ Bw,
    float* __restrict__ C, const float* __restrict__ res,
    int N, int K){
  __shared__ u16 As[128][36];   // +4 pad breaks pow2 bank stride
  __shared__ u16 Bs[64][36];
  const int tid = threadIdx.x;
  const int wave = tid >> 6;
  const int lane = tid & 63;
  const int q  = lane >> 4;
  const int mr = lane & 15;
  const int m0 = blockIdx.x * 128;
  const int n0 = blockIdx.y * 64;

  union FragU { u32 u[4]; bf16x8 v; };
  f32x4 zero = {0.f, 0.f, 0.f, 0.f};
  f32x4 acc[2][4];
  #pragma unroll
  for (int i = 0; i < 2; i++)
    #pragma unroll
    for (int j = 0; j < 4; j++) acc[i][j] = zero;

  for (int k0 = 0; k0 < K; k0 += 32){
    #pragma unroll
    for (int p = 0; p < 2; ++p){         // A: 128 rows x 4 16B-chunks
      int ch = p*256 + tid;
      int r = ch >> 2, c4 = ch & 3;
      const uint4 val = *(const uint4*)(&A[(size_t)(m0 + r)*K + k0 + c4*8]);
      u32* dst = (u32*)&As[r][c4*8];
      dst[0]=val.x; dst[1]=val.y; dst[2]=val.z; dst[3]=val.w;
    }
    {                                    // B: 64 rows x 4 chunks
      int r = tid >> 2, c4 = tid & 3;
      const uint4 val = *(const uint4*)(&Bw[(size_t)(n0 + r)*K + k0 + c4*8]);
      u32* dst = (u32*)&Bs[r][c4*8];
      dst[0]=val.x; dst[1]=val.y; dst[2]=val.z; dst[3]=val.w;
    }
    __syncthreads();
    bf16x8 afr[2], bfr[4];
    #pragma unroll
    for (int mt = 0; mt < 2; mt++){
      const u32* p = (const u32*)&As[wave*32 + mt*16 + mr][q*8];
      FragU f; f.u[0]=p[0]; f.u[1]=p[1]; f.u[2]=p[2]; f.u[3]=p[3];
      afr[mt] = f.v;
    }
    #pragma unroll
    for (int nt = 0; nt < 4; nt++){
      const u32* p = (const u32*)&Bs[nt*16 + mr][q*8];
      FragU f; f.u[0]=p[0]; f.u[1]=p[1]; f.u[2]=p[2]; f.u[3]=p[3];
      bfr[nt] = f.v;
    }
    #pragma unroll
    for (int mt = 0; mt < 2; mt++)
      #pragma unroll
      for (int nt = 0; nt < 4; nt++)
        acc[mt][nt] = __builtin_amdgcn_mfma_f32_16x16x32_bf16(
            afr[mt], bfr[nt], acc[mt][nt], 0, 0, 0);
    __syncthreads();
  }

  #pragma unroll
  for (int mt = 0; mt < 2; mt++)
    #pragma unroll
    for (int nt = 0; nt < 4; nt++)
      #pragma unroll
      for (int r = 0; r < 4; r++){
        int row = m0 + wave*32 + mt*16 + q*4 + r;
        int col = n0 + nt*16 + mr;
        size_t idx = (size_t)row * N + col;
        float v = acc[mt][nt][r];
        if (res) v += res[idx];
        C[idx] = v;
      }
}

// ------------- split proj (M x 704) into q_lat(bf16), kn(f32), v_lat(bf16),
//               alpha = sigmoid(.+bias) (f32).  One wave per row. -------------
__global__ __launch_bounds__(256) void split_proj(
    const float* __restrict__ proj, const float* __restrict__ Wab,
    u16* __restrict__ qlatb, float* __restrict__ knf,
    u16* __restrict__ vlatb, float* __restrict__ alphaf){
  const int m = blockIdx.x * 4 + (threadIdx.x >> 6);
  const int lane = threadIdx.x & 63;
  const float* pr = proj + (size_t)m * 704;
  qlatb[(size_t)m*64 + lane] = f2bf(pr[lane]);
  float kv = pr[64 + lane];
  float ss = kv * kv;
  #pragma unroll
  for (int off = 32; off > 0; off >>= 1) ss += __shfl_xor(ss, off, 64);
  float nrm = fmaxf(sqrtf(ss), 1e-12f);
  knf[(size_t)m*64 + lane] = kv / nrm;
  vlatb[(size_t)m*64 + lane] = f2bf(pr[128 + lane]);
  #pragma unroll
  for (int j = 0; j < 8; j++){
    int jj = j*64 + lane;
    float av = pr[192 + jj] + Wab[jj];
    alphaf[(size_t)m*512 + jj] = 1.f / (1.f + expf(-av));
  }
}

// ------------- gated linear-attention scan (fp32, sequential in t) ----------
// grid = B*H blocks, 128 threads (lane = d). S[c][d] column in VGPRs.
// q,alpha: (M,512) col h*64+c ; kn: (M,64) ; v: (M,1024) col h*128+d
// o (bf16): (M,1024) col h*128+d
__global__ __launch_bounds__(128) void recurrence_kernel(
    const float* __restrict__ qf, const float* __restrict__ knf,
    const float* __restrict__ vf, const float* __restrict__ alphaf,
    u16* __restrict__ ob){
  const int bh = blockIdx.x;
  const int b = bh >> 3, h = bh & 7;
  const int tid = threadIdx.x;
  __shared__ __align__(16) float sQ[2][64];
  __shared__ __align__(16) float sK[2][64];
  __shared__ __align__(16) float sA[2][64];
  __shared__ __align__(16) float sV[2][128];

  const float* qbase = qf     + ((size_t)b*T_)*512 + h*64;
  const float* abase = alphaf + ((size_t)b*T_)*512 + h*64;
  const float* kbase = knf    + ((size_t)b*T_)*64;
  const float* vbase = vf     + ((size_t)b*T_)*1024 + h*128;
  u16*         obase = ob     + ((size_t)b*T_)*1024 + h*128;

  float S[64];
  #pragma unroll
  for (int c = 0; c < 64; c++) S[c] = 0.f;

  // prologue: stage t=0
  float rv = vbase[tid], rq = 0.f, ra = 0.f, rk = 0.f;
  if (tid < 64){ rq = qbase[tid]; ra = abase[tid]; }
  else         { rk = kbase[tid - 64]; }
  sV[0][tid] = rv;
  if (tid < 64){ sQ[0][tid] = rq; sA[0][tid] = ra; }
  else         { sK[0][tid - 64] = rk; }
  __syncthreads();

  for (int t = 0; t < T_; t++){
    const int cur = t & 1, nxt = cur ^ 1;
    if (t + 1 < T_){   // prefetch next timestep (latency hidden behind compute)
      rv = vbase[(size_t)(t+1)*1024 + tid];
      if (tid < 64){
        rq = qbase[(size_t)(t+1)*512 + tid];
        ra = abase[(size_t)(t+1)*512 + tid];
      } else {
        rk = kbase[(size_t)(t+1)*64 + tid - 64];
      }
    }
    const float vd = sV[cur][tid];
    float o = 0.f;
    #pragma unroll
    for (int c4 = 0; c4 < 16; c4++){
      float4 a4 = *(const float4*)&sA[cur][c4*4];
      float4 k4 = *(const float4*)&sK[cur][c4*4];
      float4 q4 = *(const float4*)&sQ[cur][c4*4];
      S[c4*4+0] = a4.x*S[c4*4+0] + k4.x*vd;  o += S[c4*4+0]*q4.x;
      S[c4*4+1] = a4.y*S[c4*4+1] + k4.y*vd;  o += S[c4*4+1]*q4.y;
      S[c4*4+2] = a4.z*S[c4*4+2] + k4.z*vd;  o += S[c4*4+2]*q4.z;
      S[c4*4+3] = a4.w*S[c4*4+3] + k4.w*vd;  o += S[c4*4+3]*q4.w;
    }
    obase[(size_t)t*1024 + tid] = f2bf(o);
    if (t + 1 < T_){
      sV[nxt][tid] = rv;
      if (tid < 64){ sQ[nxt][tid] = rq; sA[nxt][tid] = ra; }
      else         { sK[nxt][tid - 64] = rk; }
    }
    __syncthreads();
  }
}

// ----------------------------- launch -----------------------------
extern "C" void kernel_launch(void* const* d_in, const int* in_sizes, int n_in,
                              void* d_out, int out_size, void* d_ws, size_t ws_size,
                              hipStream_t stream){
  const float* x     = (const float*)d_in[0];
  const float* Wq    = (const float*)d_in[1];
  const float* Wk    = (const float*)d_in[2];
  const float* Wv    = (const float*)d_in[3];
  const float* Qc    = (const float*)d_in[4];
  const float* Vc    = (const float*)d_in[5];
  const float* Wa_w  = (const float*)d_in[6];
  const float* Wa_b  = (const float*)d_in[7];
  const float* Wo    = (const float*)d_in[8];
  const float* gamma = (const float*)d_in[9];
  const float* beta  = (const float*)d_in[10];
  float* out = (float*)d_out;

  char* ws = (char*)d_ws;
  size_t off = 0;
  auto alloc = [&](size_t bytes) -> void* {
    void* p = ws + off; off += (bytes + 255) & ~(size_t)255; return p;
  };
  // R1: xnb (bf16, M*1024) then reused as qf (f32, M*512) - same 33.5MB
  char* R1 = (char*)alloc((size_t)M_ * 1024 * 2);
  u16*   xnb = (u16*)R1;
  float* qf  = (float*)R1;
  // R2: proj (f32, M*704) then reused as ob (bf16, M*1024)
  char* R2 = (char*)alloc((size_t)M_ * 704 * 4);
  float* proj = (float*)R2;
  u16*   obuf = (u16*)R2;
  float* vf     = (float*)alloc((size_t)M_ * 1024 * 4);
  u16*   Wcatb  = (u16*)alloc((size_t)704 * 1024 * 2);
  u16*   QcTb   = (u16*)alloc((size_t)512 * 64 * 2);
  u16*   VcTb   = (u16*)alloc((size_t)1024 * 64 * 2);
  u16*   Wob    = (u16*)alloc((size_t)1024 * 1024 * 2);
  u16*   qlatb  = (u16*)alloc((size_t)M_ * 64 * 2);
  u16*   vlatb  = (u16*)alloc((size_t)M_ * 64 * 2);
  float* knf    = (float*)alloc((size_t)M_ * 64 * 4);
  float* alphaf = (float*)alloc((size_t)M_ * 512 * 4);
  (void)ws_size; (void)in_sizes; (void)n_in; (void)out_size;

  ln_kernel<<<dim3(M_), dim3(256), 0, stream>>>(x, gamma, beta, xnb);
  prep_weights<<<dim3(7296), dim3(256), 0, stream>>>(
      Wq, Wk, Wv, Wa_w, Qc, Vc, Wo, Wcatb, QcTb, VcTb, Wob);
  // proj = xn @ Wcat^T : (M,704)
  gemm_bf16<<<dim3(M_/128, 704/64), dim3(256), 0, stream>>>(
      xnb, Wcatb, proj, nullptr, 704, 1024);
  split_proj<<<dim3(M_/4), dim3(256), 0, stream>>>(
      proj, Wa_b, qlatb, knf, vlatb, alphaf);
  // q = q_lat @ QcT^T : (M,512) layout (b,t,h,e)
  gemm_bf16<<<dim3(M_/128, 512/64), dim3(256), 0, stream>>>(
      qlatb, QcTb, qf, nullptr, 512, 64);
  // v = v_lat @ VcT^T : (M,1024) layout (b,t,h,d)
  gemm_bf16<<<dim3(M_/128, 1024/64), dim3(256), 0, stream>>>(
      vlatb, VcTb, vf, nullptr, 1024, 64);
  recurrence_kernel<<<dim3(B_*H_), dim3(128), 0, stream>>>(
      qf, knf, vf, alphaf, obuf);
  // out = o @ Wo^T + x : (M,1024)
  gemm_bf16<<<dim3(M_/128, 1024/64), dim3(256), 0, stream>>>(
      obuf, Wob, out, x, 1024, 1024);
}